// Round 1
// baseline (111.360 us; speedup 1.0000x reference)
//
#include <hip/hip_runtime.h>

// Lorenz-96 vector field:
//   field[b,i] = p0[i]*(s[b,i+1] - s[b,i-2])*s[b,i-1] - p1[i]*s[b,i] + p2[i]
// with circular indexing over DIM=256.
//
// Layout: one wave (64 lanes) per row; each lane owns 4 consecutive elements
// (float4). Neighbor elements for the circular shifts come from adjacent
// lanes via __shfl — no LDS, no __syncthreads. Params (3x256 fp32) are loaded
// once per thread and reused across a grid-stride loop over rows.

#define DIM 256

__global__ __launch_bounds__(256) void lorenz96_kernel(
    const float* __restrict__ state,
    const float* __restrict__ params,
    float* __restrict__ out,
    int nrows)
{
    const int lane        = threadIdx.x & 63;          // lane within wave
    const int waveInBlock = threadIdx.x >> 6;          // 0..3
    const int wavesTotal  = gridDim.x * (blockDim.x >> 6);
    const int waveId      = blockIdx.x * (blockDim.x >> 6) + waveInBlock;

    // Per-lane parameter fragments for columns [4*lane .. 4*lane+3].
    const float4 p0 = reinterpret_cast<const float4*>(params          )[lane];
    const float4 p1 = reinterpret_cast<const float4*>(params + DIM    )[lane];
    const float4 p2 = reinterpret_cast<const float4*>(params + 2 * DIM)[lane];

    const int laneM1 = (lane + 63) & 63;
    const int laneP1 = (lane + 1) & 63;

    for (int row = waveId; row < nrows; row += wavesTotal) {
        const float4 s =
            reinterpret_cast<const float4*>(state + (size_t)row * DIM)[lane];

        // Cross-lane neighbors (circular over the 64-lane wave = 256 cols):
        const float nW = __shfl(s.w, laneM1, 64);  // s[4l-1]
        const float nZ = __shfl(s.z, laneM1, 64);  // s[4l-2]
        const float nX = __shfl(s.x, laneP1, 64);  // s[4l+4]

        float4 f;
        // i = 4l   : s+1 = s.y, s-2 = nZ,  s-1 = nW
        f.x = p0.x * (s.y - nZ ) * nW  - p1.x * s.x + p2.x;
        // i = 4l+1 : s+1 = s.z, s-2 = nW,  s-1 = s.x
        f.y = p0.y * (s.z - nW ) * s.x - p1.y * s.y + p2.y;
        // i = 4l+2 : s+1 = s.w, s-2 = s.x, s-1 = s.y
        f.z = p0.z * (s.w - s.x) * s.y - p1.z * s.z + p2.z;
        // i = 4l+3 : s+1 = nX,  s-2 = s.y, s-1 = s.z
        f.w = p0.w * (nX  - s.y) * s.z - p1.w * s.w + p2.w;

        reinterpret_cast<float4*>(out + (size_t)row * DIM)[lane] = f;
    }
}

extern "C" void kernel_launch(void* const* d_in, const int* in_sizes, int n_in,
                              void* d_out, int out_size, void* d_ws, size_t ws_size,
                              hipStream_t stream) {
    const float* state  = (const float*)d_in[0];   // (B, 256) fp32
    const float* params = (const float*)d_in[1];   // (3, 256) fp32
    // d_in[2] = t, unused by the vector field.
    float* out = (float*)d_out;

    const int nrows = in_sizes[0] / DIM;           // B = 262144

    // Memory-bound streaming: ~8 blocks/CU, grid-stride the rest.
    const int block = 256;
    int rowsBlocks = (nrows + 3) / 4;              // 4 waves (rows) per block
    int grid = rowsBlocks < 2048 ? rowsBlocks : 2048;

    lorenz96_kernel<<<grid, block, 0, stream>>>(state, params, out, nrows);
}

// Round 3
// 95.324 us; speedup vs baseline: 1.1682x; 1.1682x over previous
//
#include <hip/hip_runtime.h>

// Lorenz-96 vector field:
//   field[b,i] = p0[i]*(s[b,i+1] - s[b,i-2])*s[b,i-1] - p1[i]*s[b,i] + p2[i]
// circular over DIM=256.
//
// One wave (64 lanes) per row, 4 floats per lane; circular-shift neighbors via
// __shfl (no LDS, no barriers). R3 = R2 with native clang vector type so the
// nontemporal builtins compile:
//  - nontemporal loads/stores (streaming, no cache allocation)
//  - 2 rows per wave per iteration (2 independent 16B loads in flight)

#define DIM 256

typedef float fx4 __attribute__((ext_vector_type(4)));

__device__ __forceinline__ fx4 lorenz_row(const fx4 s,
                                          const fx4 p0,
                                          const fx4 p1,
                                          const fx4 p2,
                                          int laneM1, int laneP1)
{
    const float nW = __shfl(s.w, laneM1, 64);  // s[4l-1]
    const float nZ = __shfl(s.z, laneM1, 64);  // s[4l-2]
    const float nX = __shfl(s.x, laneP1, 64);  // s[4l+4]

    fx4 f;
    f.x = p0.x * (s.y - nZ ) * nW  - p1.x * s.x + p2.x;
    f.y = p0.y * (s.z - nW ) * s.x - p1.y * s.y + p2.y;
    f.z = p0.z * (s.w - s.x) * s.y - p1.z * s.z + p2.z;
    f.w = p0.w * (nX  - s.y) * s.z - p1.w * s.w + p2.w;
    return f;
}

__global__ __launch_bounds__(256) void lorenz96_kernel(
    const float* __restrict__ state,
    const float* __restrict__ params,
    float* __restrict__ out,
    int nrows)
{
    const int lane        = threadIdx.x & 63;
    const int waveInBlock = threadIdx.x >> 6;
    const int wavesTotal  = gridDim.x * (blockDim.x >> 6);
    const int waveId      = blockIdx.x * (blockDim.x >> 6) + waveInBlock;

    const fx4* __restrict__ pp = reinterpret_cast<const fx4*>(params);
    const fx4 p0 = pp[lane];
    const fx4 p1 = pp[64 + lane];
    const fx4 p2 = pp[128 + lane];

    const int laneM1 = (lane + 63) & 63;
    const int laneP1 = (lane + 1) & 63;

    const fx4* __restrict__ sp = reinterpret_cast<const fx4*>(state);
    fx4* __restrict__       op = reinterpret_cast<fx4*>(out);

    int row = waveId * 2;
    const int stride = wavesTotal * 2;

    for (; row + 1 < nrows; row += stride) {
        // Two independent rows: both loads issue before either shfl chain.
        const fx4 sA = __builtin_nontemporal_load(&sp[(size_t)row * 64 + lane]);
        const fx4 sB = __builtin_nontemporal_load(&sp[((size_t)row + 1) * 64 + lane]);

        const fx4 fA = lorenz_row(sA, p0, p1, p2, laneM1, laneP1);
        const fx4 fB = lorenz_row(sB, p0, p1, p2, laneM1, laneP1);

        __builtin_nontemporal_store(fA, &op[(size_t)row * 64 + lane]);
        __builtin_nontemporal_store(fB, &op[((size_t)row + 1) * 64 + lane]);
    }
    if (row < nrows) {  // tail (nrows odd — not hit for B=262144)
        const fx4 sA = __builtin_nontemporal_load(&sp[(size_t)row * 64 + lane]);
        const fx4 fA = lorenz_row(sA, p0, p1, p2, laneM1, laneP1);
        __builtin_nontemporal_store(fA, &op[(size_t)row * 64 + lane]);
    }
}

extern "C" void kernel_launch(void* const* d_in, const int* in_sizes, int n_in,
                              void* d_out, int out_size, void* d_ws, size_t ws_size,
                              hipStream_t stream) {
    const float* state  = (const float*)d_in[0];   // (B, 256) fp32
    const float* params = (const float*)d_in[1];   // (3, 256) fp32
    float* out = (float*)d_out;

    const int nrows = in_sizes[0] / DIM;           // B = 262144

    const int block = 256;                          // 4 waves/block
    // 2 rows per wave per iter -> 8 rows/block/iter.
    int need = (nrows + 7) / 8;
    int grid = need < 2048 ? need : 2048;

    lorenz96_kernel<<<grid, block, 0, stream>>>(state, params, out, nrows);
}

// Round 4
// 94.628 us; speedup vs baseline: 1.1768x; 1.0074x over previous
//
#include <hip/hip_runtime.h>

// Lorenz-96 vector field:
//   field[b,i] = p0[i]*(s[b,i+1] - s[b,i-2])*s[b,i-1] - p1[i]*s[b,i] + p2[i]
// circular over DIM=256.
//
// One wave (64 lanes) per row, 4 floats per lane; circular-shift neighbors via
// __shfl (no LDS, no barriers). R4 = R3 with 4 rows per wave per iteration:
// 4 independent nontemporal loads in flight -> deeper MLP, shfl/ALU of each
// row hides under the loads of the others.

#define DIM 256

typedef float fx4 __attribute__((ext_vector_type(4)));

__device__ __forceinline__ fx4 lorenz_row(const fx4 s,
                                          const fx4 p0,
                                          const fx4 p1,
                                          const fx4 p2,
                                          int laneM1, int laneP1)
{
    const float nW = __shfl(s.w, laneM1, 64);  // s[4l-1]
    const float nZ = __shfl(s.z, laneM1, 64);  // s[4l-2]
    const float nX = __shfl(s.x, laneP1, 64);  // s[4l+4]

    fx4 f;
    f.x = p0.x * (s.y - nZ ) * nW  - p1.x * s.x + p2.x;
    f.y = p0.y * (s.z - nW ) * s.x - p1.y * s.y + p2.y;
    f.z = p0.z * (s.w - s.x) * s.y - p1.z * s.z + p2.z;
    f.w = p0.w * (nX  - s.y) * s.z - p1.w * s.w + p2.w;
    return f;
}

__global__ __launch_bounds__(256) void lorenz96_kernel(
    const float* __restrict__ state,
    const float* __restrict__ params,
    float* __restrict__ out,
    int nrows)
{
    const int lane        = threadIdx.x & 63;
    const int waveInBlock = threadIdx.x >> 6;
    const int wavesTotal  = gridDim.x * (blockDim.x >> 6);
    const int waveId      = blockIdx.x * (blockDim.x >> 6) + waveInBlock;

    const fx4* __restrict__ pp = reinterpret_cast<const fx4*>(params);
    const fx4 p0 = pp[lane];
    const fx4 p1 = pp[64 + lane];
    const fx4 p2 = pp[128 + lane];

    const int laneM1 = (lane + 63) & 63;
    const int laneP1 = (lane + 1) & 63;

    const fx4* __restrict__ sp = reinterpret_cast<const fx4*>(state);
    fx4* __restrict__       op = reinterpret_cast<fx4*>(out);

    int row = waveId * 4;
    const int stride = wavesTotal * 4;

    for (; row + 3 < nrows; row += stride) {
        const size_t base = (size_t)row * 64 + lane;
        // Four independent rows: all loads issue before any shfl chain.
        const fx4 sA = __builtin_nontemporal_load(&sp[base      ]);
        const fx4 sB = __builtin_nontemporal_load(&sp[base +  64]);
        const fx4 sC = __builtin_nontemporal_load(&sp[base + 128]);
        const fx4 sD = __builtin_nontemporal_load(&sp[base + 192]);

        const fx4 fA = lorenz_row(sA, p0, p1, p2, laneM1, laneP1);
        const fx4 fB = lorenz_row(sB, p0, p1, p2, laneM1, laneP1);
        const fx4 fC = lorenz_row(sC, p0, p1, p2, laneM1, laneP1);
        const fx4 fD = lorenz_row(sD, p0, p1, p2, laneM1, laneP1);

        __builtin_nontemporal_store(fA, &op[base      ]);
        __builtin_nontemporal_store(fB, &op[base +  64]);
        __builtin_nontemporal_store(fC, &op[base + 128]);
        __builtin_nontemporal_store(fD, &op[base + 192]);
    }
    for (; row < nrows; ++row) {  // tail (not hit for B=262144)
        const size_t base = (size_t)row * 64 + lane;
        const fx4 sA = __builtin_nontemporal_load(&sp[base]);
        const fx4 fA = lorenz_row(sA, p0, p1, p2, laneM1, laneP1);
        __builtin_nontemporal_store(fA, &op[base]);
    }
}

extern "C" void kernel_launch(void* const* d_in, const int* in_sizes, int n_in,
                              void* d_out, int out_size, void* d_ws, size_t ws_size,
                              hipStream_t stream) {
    const float* state  = (const float*)d_in[0];   // (B, 256) fp32
    const float* params = (const float*)d_in[1];   // (3, 256) fp32
    float* out = (float*)d_out;

    const int nrows = in_sizes[0] / DIM;           // B = 262144

    const int block = 256;                          // 4 waves/block
    // 4 rows per wave per iter -> 16 rows/block/iter.
    int need = (nrows + 15) / 16;
    int grid = need < 2048 ? need : 2048;

    lorenz96_kernel<<<grid, block, 0, stream>>>(state, params, out, nrows);
}